// Round 4
// baseline (1024.535 us; speedup 1.0000x reference)
//
#include <hip/hip_runtime.h>

// Problem constants (GRID=192, ISO=0)
#define GN 192           // grid points per axis
#define CN 193           // cells per axis (GN+1)
#define CN2 (CN * CN)    // 37249
#define QPOS 49          // k-positions per row (4 cells each): 49*4 >= 193
#define NPOS ((size_t)CN * CN * QPOS)   // 1,825,201 threads

// Output layout (float32 elements), in reference return order:
#define NV        ((size_t)CN * CN * CN)                  // 7,189,057
#define OFF_VMASK ((size_t)(NV * 3))                      // 21,567,171
#define OFF_QUADS ((size_t)(OFF_VMASK + NV))              // 28,756,228 (mod 4 == 0)
#define QSEG      ((size_t)CN * GN * GN)                  // 7,114,752 rows per segment
#define OFF_QMASK ((size_t)(OFF_QUADS + 3 * QSEG * 4))    // 114,133,252 (mod 4 == 0)

typedef float v4f __attribute__((ext_vector_type(4)));   // native vector: OK for nontemporal builtins

// Load 5 consecutive padded values of row (x,y): z = k0-1 .. k0+3.
// Row OOB (x or y outside grid) -> all pad (iso+1 = 1.0f).
__device__ __forceinline__ void load_row(const float* __restrict__ g, int x, int y,
                                         int k0, float r[5]) {
    if ((unsigned)x < (unsigned)GN && (unsigned)y < (unsigned)GN) {
        const float* rp = g + ((size_t)x * GN + y) * GN;
        r[0] = (k0 > 0) ? rp[k0 - 1] : 1.0f;
        if (k0 < GN) {                      // k0 multiple of 4 -> k0+3 <= 191 here
            const v4f v = *(const v4f*)(rp + k0);   // 16B-aligned
            r[1] = v.x; r[2] = v.y; r[3] = v.z; r[4] = v.w;
        } else {                            // k0 == 192 (q == 48)
            r[1] = r[2] = r[3] = r[4] = 1.0f;
        }
    } else {
        r[0] = r[1] = r[2] = r[3] = r[4] = 1.0f;
    }
}

__global__ __launch_bounds__(256) void dmc_fused(const float* __restrict__ g,
                                                 float* __restrict__ out) {
    const size_t t = (size_t)blockIdx.x * 256 + threadIdx.x;
    if (t >= NPOS) return;
    const int ti = (int)t;
    const int q  = ti % QPOS;         // k-position within row
    const int rj = ti / QPOS;         // i*CN + j
    const int j  = rj % CN;
    const int i  = rj / CN;
    const int k0 = q * 4;

    // 4 grid rows covering the 2x2 (x,y) corner footprint of cells k0..k0+3
    float r00[5], r10[5], r01[5], r11[5];
    load_row(g, i - 1, j - 1, k0, r00);
    load_row(g, i,     j - 1, k0, r10);
    load_row(g, i - 1, j,     k0, r01);
    load_row(g, i,     j,     k0, r11);

    const int ncell = (q < 48) ? 4 : 1;       // q==48 handles only k=192
    const int cellbase = rj * CN + k0;        // linear cell id of cell c=0
    const float flin0 = (float)cellbase;      // exact: < 2^24

    float mA[4], mB[4], mC[4];

    #pragma unroll
    for (int c = 0; c < 4; ++c) {
        const float v000 = r00[c], v001 = r00[c + 1];
        const float v100 = r10[c], v101 = r10[c + 1];
        const float v010 = r01[c], v011 = r01[c + 1];
        const float v110 = r11[c], v111 = r11[c + 1];
        const bool s000 = v000 < 0.f, s100 = v100 < 0.f, s010 = v010 < 0.f, s110 = v110 < 0.f;
        const bool s001 = v001 < 0.f, s101 = v101 < 0.f, s011 = v011 < 0.f, s111 = v111 < 0.f;

        mA[c] = (s011 != s111) ? 1.0f : 0.0f;
        mB[c] = (s001 != s011) ? 1.0f : 0.0f;
        mC[c] = (s000 != s001) ? 1.0f : 0.0f;

        float sx = 0.f, sy = 0.f, sz = 0.f;
        int cnt = 0;
        auto acc = [&](float vA, float vB, bool sA, bool sB, int axis, float o1, float o2) {
            if (sA != sB) {
                const float tt = -vA * __builtin_amdgcn_rcpf(vB - vA);
                if (axis == 0)      { sx += tt; sy += o1; sz += o2; }
                else if (axis == 1) { sx += o1; sy += tt; sz += o2; }
                else                { sx += o1; sy += o2; sz += tt; }
                cnt++;
            }
        };
        acc(v000, v100, s000, s100, 0, 0.f, 0.f);
        acc(v010, v110, s010, s110, 0, 1.f, 0.f);
        acc(v001, v101, s001, s101, 0, 0.f, 1.f);
        acc(v011, v111, s011, s111, 0, 1.f, 1.f);
        acc(v000, v010, s000, s010, 1, 0.f, 0.f);
        acc(v100, v110, s100, s110, 1, 1.f, 0.f);
        acc(v001, v011, s001, s011, 1, 0.f, 1.f);
        acc(v101, v111, s101, s111, 1, 1.f, 1.f);
        acc(v000, v001, s000, s001, 2, 0.f, 0.f);
        acc(v100, v101, s100, s101, 2, 1.f, 0.f);
        acc(v010, v011, s010, s011, 2, 0.f, 1.f);
        acc(v110, v111, s110, s111, 2, 1.f, 1.f);

        if (c < ncell) {
            const float rc = __builtin_amdgcn_rcpf(fmaxf((float)cnt, 1.0f));
            const float inv191 = 1.0f / 191.0f;
            const int k = k0 + c;
            const size_t vb = (size_t)(cellbase + c) * 3;
            out[vb + 0] = ((float)i + sx * rc - 1.0f) * inv191;
            out[vb + 1] = ((float)j + sy * rc - 1.0f) * inv191;
            out[vb + 2] = ((float)k + sz * rc - 1.0f) * inv191;
            out[OFF_VMASK + cellbase + c] = (cnt > 0) ? 1.0f : 0.0f;
        }
    }

    v4f* const quads = (v4f*)(out + OFF_QUADS);
    float* const qmask = out + OFF_QMASK;

    // ---- segment A: x-edges. Needs j<192 && k<192 (uniform over the 4 cells).
    if (j < GN && q < 48) {
        const size_t rA = ((size_t)i * GN + j) * GN + k0;   // divisible by 4
        #pragma unroll
        for (int c = 0; c < 4; ++c) {
            const float f = flin0 + (float)c;
            v4f qd = {f, f + (float)CN, f + (float)(CN + 1), f + 1.0f};
            __builtin_nontemporal_store(qd, quads + rA + c);
        }
        v4f mv = {mA[0], mA[1], mA[2], mA[3]};
        __builtin_nontemporal_store(mv, (v4f*)(qmask + rA));
    }
    // ---- segment B: y-edges. Needs i>=1 && k<192.
    if (i >= 1 && q < 48) {
        const size_t rB = QSEG + ((size_t)(i - 1) * CN + j) * GN + k0;  // div by 4
        #pragma unroll
        for (int c = 0; c < 4; ++c) {
            const float f = flin0 + (float)c;
            v4f qd = {f - (float)CN2, f, f + 1.0f, f - (float)(CN2 - 1)};
            __builtin_nontemporal_store(qd, quads + rB + c);
        }
        v4f mv = {mB[0], mB[1], mB[2], mB[3]};
        __builtin_nontemporal_store(mv, (v4f*)(qmask + rB));
    }
    // ---- segment C: z-edges. Needs i>=1 && j>=1; per-cell k<=192.
    if (i >= 1 && j >= 1) {
        const size_t rC = 2 * QSEG + ((size_t)(i - 1) * GN + (j - 1)) * CN + k0;
        #pragma unroll
        for (int c = 0; c < 4; ++c) {
            if (c < ncell) {
                const float f = flin0 + (float)c;
                v4f qd = {f - (float)(CN2 + CN), f - (float)CN, f, f - (float)CN2};
                __builtin_nontemporal_store(qd, quads + rC + c);
                qmask[rC + c] = mC[c];     // row base odd-strided: scalar, let L2 merge
            }
        }
    }
}

extern "C" void kernel_launch(void* const* d_in, const int* in_sizes, int n_in,
                              void* d_out, int out_size, void* d_ws, size_t ws_size,
                              hipStream_t stream) {
    const float* g = (const float*)d_in[0];
    float* out = (float*)d_out;
    const int nblocks = (int)((NPOS + 255) / 256);   // 7130
    dmc_fused<<<dim3(nblocks), dim3(256), 0, stream>>>(g, out);
}

// Round 5
// 607.913 us; speedup vs baseline: 1.6853x; 1.6853x over previous
//
#include <hip/hip_runtime.h>

// Problem constants (GRID=192, ISO=0)
#define GN 192           // grid points per axis
#define CN 193           // cells per axis (GN+1)
#define CN2 (CN * CN)    // 37249
#define QPOS 49          // k-positions per row (4 cells each): 49*4 >= 193
#define NPOS ((size_t)CN * CN * QPOS)   // 1,825,201 threads

// Output layout (float32 elements), in reference return order:
#define NV        ((size_t)CN * CN * CN)                  // 7,189,057
#define OFF_VMASK ((size_t)(NV * 3))                      // 21,567,171
#define OFF_QUADS ((size_t)(OFF_VMASK + NV))              // 28,756,228 (mod 4 == 0)
#define QSEG      ((size_t)CN * GN * GN)                  // 7,114,752 rows per segment
#define OFF_QMASK ((size_t)(OFF_QUADS + 3 * QSEG * 4))    // 114,133,252 (mod 4 == 0)

typedef float v4f __attribute__((ext_vector_type(4)));

// Load 5 consecutive padded values of row (x,y): z = k0-1 .. k0+3.
// Row OOB (x or y outside grid) -> all pad (iso+1 = 1.0f).
__device__ __forceinline__ void load_row(const float* __restrict__ g, int x, int y,
                                         int k0, float r[5]) {
    if ((unsigned)x < (unsigned)GN && (unsigned)y < (unsigned)GN) {
        const float* rp = g + ((size_t)x * GN + y) * GN;
        r[0] = (k0 > 0) ? rp[k0 - 1] : 1.0f;
        if (k0 < GN) {                      // k0 multiple of 4 -> k0+3 <= 191 here
            const v4f v = *(const v4f*)(rp + k0);   // 16B-aligned
            r[1] = v.x; r[2] = v.y; r[3] = v.z; r[4] = v.w;
        } else {                            // k0 == 192 (q == 48)
            r[1] = r[2] = r[3] = r[4] = 1.0f;
        }
    } else {
        r[0] = r[1] = r[2] = r[3] = r[4] = 1.0f;
    }
}

__global__ __launch_bounds__(256) void dmc_fused(const float* __restrict__ g,
                                                 float* __restrict__ out) {
    const size_t t = (size_t)blockIdx.x * 256 + threadIdx.x;
    if (t >= NPOS) return;
    const int ti = (int)t;
    const int q  = ti % QPOS;         // k-position within row
    const int rj = ti / QPOS;         // i*CN + j
    const int j  = rj % CN;
    const int i  = rj / CN;
    const int k0 = q * 4;

    // 4 grid rows covering the 2x2 (x,y) corner footprint of cells k0..k0+3
    float r00[5], r10[5], r01[5], r11[5];
    load_row(g, i - 1, j - 1, k0, r00);
    load_row(g, i,     j - 1, k0, r10);
    load_row(g, i - 1, j,     k0, r01);
    load_row(g, i,     j,     k0, r11);

    const int ncell = (q < 48) ? 4 : 1;       // q==48 handles only k=192
    const int cellbase = rj * CN + k0;        // linear cell id of cell c=0
    const float flin0 = (float)cellbase;      // exact: < 2^24

    float mA[4], mB[4], mC[4];

    #pragma unroll
    for (int c = 0; c < 4; ++c) {
        const float v000 = r00[c], v001 = r00[c + 1];
        const float v100 = r10[c], v101 = r10[c + 1];
        const float v010 = r01[c], v011 = r01[c + 1];
        const float v110 = r11[c], v111 = r11[c + 1];
        const bool s000 = v000 < 0.f, s100 = v100 < 0.f, s010 = v010 < 0.f, s110 = v110 < 0.f;
        const bool s001 = v001 < 0.f, s101 = v101 < 0.f, s011 = v011 < 0.f, s111 = v111 < 0.f;

        mA[c] = (s011 != s111) ? 1.0f : 0.0f;
        mB[c] = (s001 != s011) ? 1.0f : 0.0f;
        mC[c] = (s000 != s001) ? 1.0f : 0.0f;

        float sx = 0.f, sy = 0.f, sz = 0.f;
        int cnt = 0;
        auto acc = [&](float vA, float vB, bool sA, bool sB, int axis, float o1, float o2) {
            if (sA != sB) {
                const float tt = -vA * __builtin_amdgcn_rcpf(vB - vA);
                if (axis == 0)      { sx += tt; sy += o1; sz += o2; }
                else if (axis == 1) { sx += o1; sy += tt; sz += o2; }
                else                { sx += o1; sy += o2; sz += tt; }
                cnt++;
            }
        };
        acc(v000, v100, s000, s100, 0, 0.f, 0.f);
        acc(v010, v110, s010, s110, 0, 1.f, 0.f);
        acc(v001, v101, s001, s101, 0, 0.f, 1.f);
        acc(v011, v111, s011, s111, 0, 1.f, 1.f);
        acc(v000, v010, s000, s010, 1, 0.f, 0.f);
        acc(v100, v110, s100, s110, 1, 1.f, 0.f);
        acc(v001, v011, s001, s011, 1, 0.f, 1.f);
        acc(v101, v111, s101, s111, 1, 1.f, 1.f);
        acc(v000, v001, s000, s001, 2, 0.f, 0.f);
        acc(v100, v101, s100, s101, 2, 1.f, 0.f);
        acc(v010, v011, s010, s011, 2, 0.f, 1.f);
        acc(v110, v111, s110, s111, 2, 1.f, 1.f);

        if (c < ncell) {
            const float rc = __builtin_amdgcn_rcpf(fmaxf((float)cnt, 1.0f));
            const float inv191 = 1.0f / 191.0f;
            const int k = k0 + c;
            const size_t vb = (size_t)(cellbase + c) * 3;
            out[vb + 0] = ((float)i + sx * rc - 1.0f) * inv191;
            out[vb + 1] = ((float)j + sy * rc - 1.0f) * inv191;
            out[vb + 2] = ((float)k + sz * rc - 1.0f) * inv191;
            out[OFF_VMASK + cellbase + c] = (cnt > 0) ? 1.0f : 0.0f;
        }
    }

    v4f* const quads = (v4f*)(out + OFF_QUADS);
    float* const qmask = out + OFF_QMASK;

    // ---- segment A: x-edges. Needs j<192 && k<192 (uniform over the 4 cells).
    if (j < GN && q < 48) {
        const size_t rA = ((size_t)i * GN + j) * GN + k0;   // divisible by 4
        #pragma unroll
        for (int c = 0; c < 4; ++c) {
            const float f = flin0 + (float)c;
            quads[rA + c] = (v4f){f, f + (float)CN, f + (float)(CN + 1), f + 1.0f};
        }
        *(v4f*)(qmask + rA) = (v4f){mA[0], mA[1], mA[2], mA[3]};
    }
    // ---- segment B: y-edges. Needs i>=1 && k<192.
    if (i >= 1 && q < 48) {
        const size_t rB = QSEG + ((size_t)(i - 1) * CN + j) * GN + k0;  // div by 4
        #pragma unroll
        for (int c = 0; c < 4; ++c) {
            const float f = flin0 + (float)c;
            quads[rB + c] = (v4f){f - (float)CN2, f, f + 1.0f, f - (float)(CN2 - 1)};
        }
        *(v4f*)(qmask + rB) = (v4f){mB[0], mB[1], mB[2], mB[3]};
    }
    // ---- segment C: z-edges. Needs i>=1 && j>=1; per-cell k<=192.
    if (i >= 1 && j >= 1) {
        const size_t rC = 2 * QSEG + ((size_t)(i - 1) * GN + (j - 1)) * CN + k0;
        #pragma unroll
        for (int c = 0; c < 4; ++c) {
            if (c < ncell) {
                const float f = flin0 + (float)c;
                quads[rC + c] = (v4f){f - (float)(CN2 + CN), f - (float)CN, f, f - (float)CN2};
                qmask[rC + c] = mC[c];     // row base odd-strided: scalar, L2 merges
            }
        }
    }
}

extern "C" void kernel_launch(void* const* d_in, const int* in_sizes, int n_in,
                              void* d_out, int out_size, void* d_ws, size_t ws_size,
                              hipStream_t stream) {
    const float* g = (const float*)d_in[0];
    float* out = (float*)d_out;
    const int nblocks = (int)((NPOS + 255) / 256);   // 7130
    dmc_fused<<<dim3(nblocks), dim3(256), 0, stream>>>(g, out);
}